// Round 4
// baseline (274.977 us; speedup 1.0000x reference)
//
#include <hip/hip_runtime.h>
#include <math.h>

// Problem constants (from reference): B=32, I=2048, O=32, C=16, U=32
#define B_   32
#define I_   2048
#define O_   32
#define C_   16
#define U_   32
#define NCOL  (O_ * U_)       // 1024 output columns (o,u)
#define TI    8               // i-values per block
#define NIG   (I_ / TI)       // 256 i-groups = partial slices
#define CQ    4               // column quarters -> grid = NIG*CQ = 1024 blocks
#define SLICE (B_ * NCOL)     // 32768 floats per partial slice
#define XS    36              // x LDS stride (floats): 36*4=144 B, mult of 16 -> aligned b128

// softmax over the singleton axis of b_log is identically 1 -> routing
// iterations are no-ops. Output = squash(sum_{i,c} x[b,i,c] * w[i,o,c,u]).
//
// R4: ~120 us of the measured time is harness reset (512 MB ws poison +
// d_in restore) - untouchable. Kernel side: 1024 blocks (256 i-groups x
// 4 col-quarters) x 512 threads, acc[4]f4 = 16 VGPR -> cap 64 VGPR at
// 8 waves/SIMD (vs 4 in R3). Partials halved to 256 slices (32 MB).
// w still HBM-fetched exactly once (cq blocks own disjoint o-ranges;
// batch-group re-reads hit L1). x LDS reads are wave-uniform broadcasts.

__global__ __launch_bounds__(512, 8) void caps_partial(const float* __restrict__ x,
                                                       const float* __restrict__ w,
                                                       float* __restrict__ ws) {
    __shared__ float xs[TI * C_ * XS];   // xs[rem*36 + b], rem = il*C + c
    const int tid = threadIdx.x;         // 0..511
    const int ig  = blockIdx.x >> 2;     // i-group
    const int cq  = blockIdx.x & 3;      // column quarter
    const int i0  = ig * TI;

    // Stage x[:, i0:i0+TI, :] -> LDS. Global coalesced (128 consecutive
    // floats per b). 8 scalar LDS writes/thread, one time (conflicts ok).
    for (int k = tid; k < B_ * TI * C_; k += 512) {
        int b   = k >> 7;                // / (TI*C_) == 128
        int rem = k & 127;
        xs[rem * XS + b] = x[(size_t)b * (I_ * C_) + (size_t)i0 * C_ + rem];
    }
    __syncthreads();

    const int colf4 = tid & 63;          // f4-column within quarter
    const int bg    = tid >> 6;          // batch group (4 batches), wave-uniform
    const int o     = cq * 8 + (colf4 >> 3);
    const int u4    = (colf4 & 7) << 2;
    const float* wp = w + o * (C_ * U_) + u4;

    float4 acc[4];
#pragma unroll
    for (int b = 0; b < 4; ++b) acc[b] = make_float4(0.f, 0.f, 0.f, 0.f);

    for (int il = 0; il < TI; ++il) {
        const float* wpi = wp + (size_t)(i0 + il) * (O_ * C_ * U_);
        const float* xr  = &xs[il * C_ * XS + bg * 4];
#pragma unroll
        for (int cc = 0; cc < C_; cc += 4) {
            float4 wv[4];
#pragma unroll
            for (int j = 0; j < 4; ++j)
                wv[j] = *(const float4*)(wpi + (cc + j) * U_);   // 16B/lane, coalesced
#pragma unroll
            for (int j = 0; j < 4; ++j) {
                float4 xq = *(const float4*)(xr + (cc + j) * XS); // broadcast b128
                acc[0].x = fmaf(xq.x, wv[j].x, acc[0].x);
                acc[0].y = fmaf(xq.x, wv[j].y, acc[0].y);
                acc[0].z = fmaf(xq.x, wv[j].z, acc[0].z);
                acc[0].w = fmaf(xq.x, wv[j].w, acc[0].w);
                acc[1].x = fmaf(xq.y, wv[j].x, acc[1].x);
                acc[1].y = fmaf(xq.y, wv[j].y, acc[1].y);
                acc[1].z = fmaf(xq.y, wv[j].z, acc[1].z);
                acc[1].w = fmaf(xq.y, wv[j].w, acc[1].w);
                acc[2].x = fmaf(xq.z, wv[j].x, acc[2].x);
                acc[2].y = fmaf(xq.z, wv[j].y, acc[2].y);
                acc[2].z = fmaf(xq.z, wv[j].z, acc[2].z);
                acc[2].w = fmaf(xq.z, wv[j].w, acc[2].w);
                acc[3].x = fmaf(xq.w, wv[j].x, acc[3].x);
                acc[3].y = fmaf(xq.w, wv[j].y, acc[3].y);
                acc[3].z = fmaf(xq.w, wv[j].z, acc[3].z);
                acc[3].w = fmaf(xq.w, wv[j].w, acc[3].w);
            }
        }
    }

    // ws[ig][b][col], col = cq*256 + colf4*4. Coalesced float4 stores.
    float* op = ws + (size_t)ig * SLICE + (size_t)(bg * 4) * NCOL + cq * 256 + colf4 * 4;
#pragma unroll
    for (int b = 0; b < 4; ++b)
        *(float4*)(op + (size_t)b * NCOL) = acc[b];
}

// Sum 256 partials per output element (2 threads/element over p-halves),
// then squash over u (32 consecutive t = one (b,o) group; shuffle reduce).
__global__ __launch_bounds__(256) void caps_reduce_squash(const float* __restrict__ ws,
                                                          float* __restrict__ out) {
    __shared__ float sh[128];
    const int tl = threadIdx.x & 127;
    const int ph = threadIdx.x >> 7;           // p-half
    const int t  = blockIdx.x * 128 + tl;      // t in [0, 32768)
    const float* p = ws + (size_t)ph * (NIG / 2) * SLICE + t;
    float s = 0.f;
#pragma unroll 16
    for (int i = 0; i < NIG / 2; ++i)
        s += p[(size_t)i * SLICE];
    if (ph) sh[tl] = s;
    __syncthreads();
    if (ph == 0) {
        s += sh[tl];
        float ss = s * s;
        ss += __shfl_xor(ss, 1);
        ss += __shfl_xor(ss, 2);
        ss += __shfl_xor(ss, 4);
        ss += __shfl_xor(ss, 8);
        ss += __shfl_xor(ss, 16);
        float n = sqrtf(ss);
        out[t] = s * n / (1.0f + ss);
    }
}

// ---------------- fallback (atomic path) if ws too small ----------------
__global__ __launch_bounds__(256, 2) void caps_main_atomic(const float* __restrict__ x,
                                                           const float* __restrict__ w,
                                                           float* __restrict__ out) {
    __shared__ float xsf[4 * C_ * 33];
    const int tid = threadIdx.x;
    const int i0 = blockIdx.x * 4;
    for (int k = tid; k < B_ * 4 * C_; k += 256) {
        int b = k >> 6, rem = k & 63;
        xsf[rem * 33 + b] = x[(size_t)b * (I_ * C_) + (size_t)i0 * C_ + rem];
    }
    __syncthreads();
    const int o = tid >> 3, u4 = (tid & 7) << 2;
    const float* wp = w + (size_t)i0 * (O_ * C_ * U_) + o * (C_ * U_) + u4;
    float4 acc[B_];
#pragma unroll
    for (int b = 0; b < B_; ++b) acc[b] = make_float4(0.f, 0.f, 0.f, 0.f);
    for (int il = 0; il < 4; ++il) {
        const float* wpi = wp + (size_t)il * (O_ * C_ * U_);
        const float* xr = &xsf[il * C_ * 33];
#pragma unroll
        for (int c = 0; c < C_; ++c) {
            float4 wv = *(const float4*)(wpi + c * U_);
            const float* xc = xr + c * 33;
#pragma unroll
            for (int b = 0; b < B_; ++b) {
                float xb = xc[b];
                acc[b].x = fmaf(xb, wv.x, acc[b].x);
                acc[b].y = fmaf(xb, wv.y, acc[b].y);
                acc[b].z = fmaf(xb, wv.z, acc[b].z);
                acc[b].w = fmaf(xb, wv.w, acc[b].w);
            }
        }
    }
    float* op = out + o * U_ + u4;
#pragma unroll
    for (int b = 0; b < B_; ++b) {
        float* p = op + (size_t)b * NCOL;
        atomicAdd(p + 0, acc[b].x);
        atomicAdd(p + 1, acc[b].y);
        atomicAdd(p + 2, acc[b].z);
        atomicAdd(p + 3, acc[b].w);
    }
}

__global__ void caps_squash_inplace(float* __restrict__ out) {
    int t = blockIdx.x * 256 + threadIdx.x;
    float s = out[t];
    float ss = s * s;
    ss += __shfl_xor(ss, 1);
    ss += __shfl_xor(ss, 2);
    ss += __shfl_xor(ss, 4);
    ss += __shfl_xor(ss, 8);
    ss += __shfl_xor(ss, 16);
    float n = sqrtf(ss);
    out[t] = s * n / (1.0f + ss);
}

extern "C" void kernel_launch(void* const* d_in, const int* in_sizes, int n_in,
                              void* d_out, int out_size, void* d_ws, size_t ws_size,
                              hipStream_t stream) {
    const float* x = (const float*)d_in[0];   // [B, I, C]
    const float* w = (const float*)d_in[1];   // [I, O, C, U]
    float* out = (float*)d_out;               // [B, O, 1, U] = 32768 floats

    const size_t need = (size_t)NIG * SLICE * sizeof(float);   // 32 MB
    if (ws_size >= need) {
        float* ws = (float*)d_ws;
        caps_partial<<<NIG * CQ, 512, 0, stream>>>(x, w, ws);
        caps_reduce_squash<<<SLICE / 128, 256, 0, stream>>>(ws, out);
    } else {
        hipMemsetAsync(out, 0, (size_t)SLICE * sizeof(float), stream);
        caps_main_atomic<<<I_ / 4, 256, 0, stream>>>(x, w, out);
        caps_squash_inplace<<<SLICE / 256, 256, 0, stream>>>(out);
    }
}

// Round 5
// 233.039 us; speedup vs baseline: 1.1800x; 1.1800x over previous
//
#include <hip/hip_runtime.h>
#include <math.h>

// Problem constants (from reference): B=32, I=2048, O=32, C=16, U=32
#define B_   32
#define I_   2048
#define O_   32
#define C_   16
#define U_   32
#define NCOL  (O_ * U_)       // 1024 output columns (o,u)
#define TI    8               // i-values per block
#define NIG   (I_ / TI)       // 256 i-groups = partial slices
#define CQ    4               // column quarters -> grid = NIG*CQ = 1024 blocks
#define SLICE (B_ * NCOL)     // 32768 floats per partial slice
#define XS    36              // x LDS stride (floats): 144 B, mult of 16 -> aligned b128

// softmax over the singleton axis of b_log is identically 1 -> routing
// iterations are no-ops. Output = squash(sum_{i,c} x[b,i,c] * w[i,o,c,u]).
//
// R5: R4's __launch_bounds__(512,8) capped VGPRs at 64 -> compiler spilled
// the accumulator to scratch (VGPR_Count=32, WRITE_SIZE 148 MB vs 33 MB of
// real partials, L2 thrash, 2.25 TB/s). Occupancy was never the constraint;
// register headroom is. Now (512,4) = 128-VGPR cap, wv[8] chunks (8
// outstanding 16B loads/thread), acc[4]f4. ~70 VGPRs live, no spill.

__global__ __launch_bounds__(512, 4) void caps_partial(const float* __restrict__ x,
                                                       const float* __restrict__ w,
                                                       float* __restrict__ ws) {
    __shared__ float xs[TI * C_ * XS];   // xs[rem*36 + b], rem = il*C + c
    const int tid = threadIdx.x;         // 0..511
    const int ig  = blockIdx.x >> 2;     // i-group
    const int cq  = blockIdx.x & 3;      // column quarter
    const int i0  = ig * TI;

    // Stage x[:, i0:i0+TI, :] -> LDS. Global coalesced (128 consecutive
    // floats per b). 8 scalar LDS writes/thread, once (conflicts negligible).
    for (int k = tid; k < B_ * TI * C_; k += 512) {
        int b   = k >> 7;                // / (TI*C_) == 128
        int rem = k & 127;
        xs[rem * XS + b] = x[(size_t)b * (I_ * C_) + (size_t)i0 * C_ + rem];
    }
    __syncthreads();

    const int colf4 = tid & 63;          // f4-column within quarter
    const int bg    = tid >> 6;          // batch group (4 batches), wave-uniform
    const int o     = cq * 8 + (colf4 >> 3);
    const int u4    = (colf4 & 7) << 2;
    const float* wp = w + o * (C_ * U_) + u4;

    float4 acc[4];
#pragma unroll
    for (int b = 0; b < 4; ++b) acc[b] = make_float4(0.f, 0.f, 0.f, 0.f);

    for (int il = 0; il < TI; ++il) {
        const float* wpi = wp + (size_t)(i0 + il) * (O_ * C_ * U_);
        const float* xr  = &xs[il * C_ * XS + bg * 4];
#pragma unroll
        for (int cc = 0; cc < C_; cc += 8) {
            float4 wv[8];
#pragma unroll
            for (int j = 0; j < 8; ++j)
                wv[j] = *(const float4*)(wpi + (cc + j) * U_);   // 16B/lane, coalesced
#pragma unroll
            for (int j = 0; j < 8; ++j) {
                float4 xq = *(const float4*)(xr + (cc + j) * XS); // broadcast b128
                acc[0].x = fmaf(xq.x, wv[j].x, acc[0].x);
                acc[0].y = fmaf(xq.x, wv[j].y, acc[0].y);
                acc[0].z = fmaf(xq.x, wv[j].z, acc[0].z);
                acc[0].w = fmaf(xq.x, wv[j].w, acc[0].w);
                acc[1].x = fmaf(xq.y, wv[j].x, acc[1].x);
                acc[1].y = fmaf(xq.y, wv[j].y, acc[1].y);
                acc[1].z = fmaf(xq.y, wv[j].z, acc[1].z);
                acc[1].w = fmaf(xq.y, wv[j].w, acc[1].w);
                acc[2].x = fmaf(xq.z, wv[j].x, acc[2].x);
                acc[2].y = fmaf(xq.z, wv[j].y, acc[2].y);
                acc[2].z = fmaf(xq.z, wv[j].z, acc[2].z);
                acc[2].w = fmaf(xq.z, wv[j].w, acc[2].w);
                acc[3].x = fmaf(xq.w, wv[j].x, acc[3].x);
                acc[3].y = fmaf(xq.w, wv[j].y, acc[3].y);
                acc[3].z = fmaf(xq.w, wv[j].z, acc[3].z);
                acc[3].w = fmaf(xq.w, wv[j].w, acc[3].w);
            }
        }
    }

    // ws[ig][b][col], col = cq*256 + colf4*4. Coalesced float4 stores
    // (64 lanes x 16B = 1 KB contiguous per store instruction).
    float* op = ws + (size_t)ig * SLICE + (size_t)(bg * 4) * NCOL + cq * 256 + colf4 * 4;
#pragma unroll
    for (int b = 0; b < 4; ++b)
        *(float4*)(op + (size_t)b * NCOL) = acc[b];
}

// Sum 256 partials per output element (2 threads/element over p-halves),
// then squash over u (32 consecutive t = one (b,o) group; shuffle reduce).
__global__ __launch_bounds__(256) void caps_reduce_squash(const float* __restrict__ ws,
                                                          float* __restrict__ out) {
    __shared__ float sh[128];
    const int tl = threadIdx.x & 127;
    const int ph = threadIdx.x >> 7;           // p-half
    const int t  = blockIdx.x * 128 + tl;      // t in [0, 32768)
    const float* p = ws + (size_t)ph * (NIG / 2) * SLICE + t;
    float s = 0.f;
#pragma unroll 16
    for (int i = 0; i < NIG / 2; ++i)
        s += p[(size_t)i * SLICE];
    if (ph) sh[tl] = s;
    __syncthreads();
    if (ph == 0) {
        s += sh[tl];
        float ss = s * s;
        ss += __shfl_xor(ss, 1);
        ss += __shfl_xor(ss, 2);
        ss += __shfl_xor(ss, 4);
        ss += __shfl_xor(ss, 8);
        ss += __shfl_xor(ss, 16);
        float n = sqrtf(ss);
        out[t] = s * n / (1.0f + ss);
    }
}

// ---------------- fallback (atomic path) if ws too small ----------------
__global__ __launch_bounds__(256, 2) void caps_main_atomic(const float* __restrict__ x,
                                                           const float* __restrict__ w,
                                                           float* __restrict__ out) {
    __shared__ float xsf[4 * C_ * 33];
    const int tid = threadIdx.x;
    const int i0 = blockIdx.x * 4;
    for (int k = tid; k < B_ * 4 * C_; k += 256) {
        int b = k >> 6, rem = k & 63;
        xsf[rem * 33 + b] = x[(size_t)b * (I_ * C_) + (size_t)i0 * C_ + rem];
    }
    __syncthreads();
    const int o = tid >> 3, u4 = (tid & 7) << 2;
    const float* wp = w + (size_t)i0 * (O_ * C_ * U_) + o * (C_ * U_) + u4;
    float4 acc[B_];
#pragma unroll
    for (int b = 0; b < B_; ++b) acc[b] = make_float4(0.f, 0.f, 0.f, 0.f);
    for (int il = 0; il < 4; ++il) {
        const float* wpi = wp + (size_t)il * (O_ * C_ * U_);
        const float* xr = &xsf[il * C_ * 33];
#pragma unroll
        for (int c = 0; c < C_; ++c) {
            float4 wv = *(const float4*)(wpi + c * U_);
            const float* xc = xr + c * 33;
#pragma unroll
            for (int b = 0; b < B_; ++b) {
                float xb = xc[b];
                acc[b].x = fmaf(xb, wv.x, acc[b].x);
                acc[b].y = fmaf(xb, wv.y, acc[b].y);
                acc[b].z = fmaf(xb, wv.z, acc[b].z);
                acc[b].w = fmaf(xb, wv.w, acc[b].w);
            }
        }
    }
    float* op = out + o * U_ + u4;
#pragma unroll
    for (int b = 0; b < B_; ++b) {
        float* p = op + (size_t)b * NCOL;
        atomicAdd(p + 0, acc[b].x);
        atomicAdd(p + 1, acc[b].y);
        atomicAdd(p + 2, acc[b].z);
        atomicAdd(p + 3, acc[b].w);
    }
}

__global__ void caps_squash_inplace(float* __restrict__ out) {
    int t = blockIdx.x * 256 + threadIdx.x;
    float s = out[t];
    float ss = s * s;
    ss += __shfl_xor(ss, 1);
    ss += __shfl_xor(ss, 2);
    ss += __shfl_xor(ss, 4);
    ss += __shfl_xor(ss, 8);
    ss += __shfl_xor(ss, 16);
    float n = sqrtf(ss);
    out[t] = s * n / (1.0f + ss);
}

extern "C" void kernel_launch(void* const* d_in, const int* in_sizes, int n_in,
                              void* d_out, int out_size, void* d_ws, size_t ws_size,
                              hipStream_t stream) {
    const float* x = (const float*)d_in[0];   // [B, I, C]
    const float* w = (const float*)d_in[1];   // [I, O, C, U]
    float* out = (float*)d_out;               // [B, O, 1, U] = 32768 floats

    const size_t need = (size_t)NIG * SLICE * sizeof(float);   // 32 MB
    if (ws_size >= need) {
        float* ws = (float*)d_ws;
        caps_partial<<<NIG * CQ, 512, 0, stream>>>(x, w, ws);
        caps_reduce_squash<<<SLICE / 128, 256, 0, stream>>>(ws, out);
    } else {
        hipMemsetAsync(out, 0, (size_t)SLICE * sizeof(float), stream);
        caps_main_atomic<<<I_ / 4, 256, 0, stream>>>(x, w, out);
        caps_squash_inplace<<<SLICE / 256, 256, 0, stream>>>(out);
    }
}